// Round 7
// baseline (2691.232 us; speedup 1.0000x reference)
//
#include <hip/hip_runtime.h>
#include <math.h>

#define N_RES 2048
#define N_IN  128
#define T_SEQ 2048
#define NB    256      // blocks in recurrence kernel (1 per CU)
#define ROWS  8        // rows per block
#define RREP  4        // x replicas
#define SENT  0x7F7F7F7Fu          // sentinel; bit30 set. |x|<=0.0222 -> clear
#define SENTM64 0x4000000040000000ULL

// ---------------- Kernel 1: U = input @ W_in^T (fallback path only) -------
__global__ __launch_bounds__(256) void u_gemm(
    const float* __restrict__ in, const float* __restrict__ win,
    float* __restrict__ out)
{
  __shared__ float As[64][65];
  __shared__ float Bs[64][65];
  const int tid = threadIdx.x;
  const int t0 = blockIdx.y * 64;
  const int n0 = blockIdx.x * 64;
  const int tx = tid & 15, ty = tid >> 4;

  float acc[4][4];
  #pragma unroll
  for (int r = 0; r < 4; ++r)
    #pragma unroll
    for (int c = 0; c < 4; ++c) acc[r][c] = 0.f;

  for (int k0 = 0; k0 < N_IN; k0 += 64) {
    __syncthreads();
    #pragma unroll
    for (int i = 0; i < 4; ++i) {
      int idx = tid + i * 256;
      int row = idx >> 4;
      int k4  = (idx & 15) << 2;
      float4 a = *(const float4*)(in  + (size_t)(t0 + row) * N_IN + k0 + k4);
      As[row][k4+0] = a.x; As[row][k4+1] = a.y; As[row][k4+2] = a.z; As[row][k4+3] = a.w;
      float4 b = *(const float4*)(win + (size_t)(n0 + row) * N_IN + k0 + k4);
      Bs[row][k4+0] = b.x; Bs[row][k4+1] = b.y; Bs[row][k4+2] = b.z; Bs[row][k4+3] = b.w;
    }
    __syncthreads();
    for (int k = 0; k < 64; ++k) {
      float a[4], b[4];
      #pragma unroll
      for (int r = 0; r < 4; ++r) a[r] = As[ty*4+r][k];
      #pragma unroll
      for (int c = 0; c < 4; ++c) b[c] = Bs[tx*4+c][k];
      #pragma unroll
      for (int r = 0; r < 4; ++r)
        #pragma unroll
        for (int c = 0; c < 4; ++c) acc[r][c] += a[r] * b[c];
    }
  }
  #pragma unroll
  for (int r = 0; r < 4; ++r) {
    float4 v = make_float4(acc[r][0], acc[r][1], acc[r][2], acc[r][3]);
    *(float4*)(out + (size_t)(t0 + ty*4 + r) * N_RES + n0 + tx*4) = v;
  }
}

// ---- DPP helpers ----------------------------------------------------------
template<int CTRL>
__device__ __forceinline__ float xdpp(float v)
{
  return __uint_as_float(__builtin_amdgcn_update_dpp(
      0, (int)__float_as_uint(v), CTRL, 0xF, 0xF, true));
}
// quad_perm[1,0,3,2] (xor1) = 0xB1 ; quad_perm[2,3,0,1] (xor2) = 0x4E
// row_ror:8 = 0x128 : within 16-lane rows, (i+8)%16 == i^8

// ---- fold-and-keep wave reduction: 8 partials -> 1 full row sum per lane.
// Lane L ends with the complete sum of row rml8(L) =
// (L&1)*4 + ((L>>1)&1)*2 + ((L>>2)&1)  (bijection on 0..7 for lanes 0..7,
// duplicated x8 across the wave).
__device__ __forceinline__ float fold_reduce8(float v[8], int lane)
{
  #pragma unroll
  for (int r = 0; r < 4; ++r) {
    float send = (lane & 1) ? v[r] : v[r + 4];
    float recv = xdpp<0xB1>(send);
    v[r] = ((lane & 1) ? v[r + 4] : v[r]) + recv;
  }
  #pragma unroll
  for (int r = 0; r < 2; ++r) {
    float send = (lane & 2) ? v[r] : v[r + 2];
    float recv = xdpp<0x4E>(send);
    v[r] = ((lane & 2) ? v[r + 2] : v[r]) + recv;
  }
  {
    float send = (lane & 4) ? v[0] : v[1];
    float recv = __shfl_xor(send, 4, 64);
    v[0] = ((lane & 4) ? v[1] : v[0]) + recv;
  }
  v[0] += xdpp<0x128>(v[0]);           // xor8 within 16-lane row (pure add)
  v[0] += __shfl_xor(v[0], 16, 64);
  v[0] += __shfl_xor(v[0], 32, 64);
  return v[0];
}

// ---- branchless fast erf (A&S 7.1.26), abs err <= 1.5e-7 ------------------
// 1/x via v_rcp_f32 (1 ULP, well below poly error). Validated R1-R6.
__device__ __forceinline__ float fast_erf(float a)
{
  float ax = fabsf(a);
  float t  = __builtin_amdgcn_rcpf(fmaf(0.3275911f, ax, 1.0f));
  float p  = fmaf(1.061405429f, t, -1.453152027f);
  p = fmaf(p, t, 1.421413741f);
  p = fmaf(p, t, -0.284496736f);
  p = fmaf(p, t, 0.254829592f);
  p *= t;
  float e = __expf(-ax * ax);
  float r = fmaf(-p, e, 1.0f);
  return copysignf(r, a);
}

// ---------------- Kernel 2: recurrence v18 (= v17 + vectorized poll) -------
// v17 substrate (measured best: 2390 us): 256 blocks x 8 rows, 4B sentinel,
// fresh lines, RREP=4, single-buffer spin, parity LDS combine, setprio,
// fused U. Changed ONLY the reader column map: thread t owns contiguous
// cols [8t, 8t+8) so the 8 spin loads become 4 x 64-bit atomic loads
// (half the L2/fabric requests per round; publish path sees less poll
// contention). Publisher code byte-identical. W_res slice remapped to
// match (2 x float4 per row, 32 B/thread contiguous).
__global__ __launch_bounds__(256, 1) void esn_recur_v18(
    const float* __restrict__ in, const float* __restrict__ win,
    const float* __restrict__ wres, float* __restrict__ out,
    unsigned int* __restrict__ xbuf)
{
  const int tid = threadIdx.x;
  const int lane = tid & 63;
  const int row0 = blockIdx.x * ROWS;
  const int wave = tid >> 6;
  const float inv = 0.022097086912079608f;   // 1/sqrt(2048)
  const int rml = (lane & 1) * 4 + ((lane >> 1) & 1) * 2 + ((lane >> 2) & 1);
  const int rb = blockIdx.x & (RREP - 1);    // replica this block polls

  // ---- W_in slice: wiA[k] = W_in[row0+rml][(lane>>3)*16 + k] -------------
  float wiA[16];
  {
    const float* wp = win + (size_t)(row0 + rml) * N_IN + ((lane >> 3) << 4);
    #pragma unroll
    for (int q = 0; q < 4; ++q) {
      float4 v = *(const float4*)(wp + 4 * q);
      wiA[4*q+0] = v.x; wiA[4*q+1] = v.y; wiA[4*q+2] = v.z; wiA[4*q+3] = v.w;
    }
  }

  // ---- u0 + x0 publish FIRST (unblocks everyone's t=1 poll early) --------
  {
    const float* ip = in + ((lane >> 3) << 4);
    float uv = 0.f;
    #pragma unroll
    for (int q = 0; q < 4; ++q) {
      float4 iv = *(const float4*)(ip + 4 * q);
      uv = fmaf(wiA[4*q+0], iv.x, uv); uv = fmaf(wiA[4*q+1], iv.y, uv);
      uv = fmaf(wiA[4*q+2], iv.z, uv); uv = fmaf(wiA[4*q+3], iv.w, uv);
    }
    uv += __shfl_xor(uv, 8, 64);
    uv += __shfl_xor(uv, 16, 64);
    uv += __shfl_xor(uv, 32, 64);
    if (tid < ROWS) {
      float x0 = fast_erf(uv) * inv;
      unsigned int xu = __float_as_uint(x0);
      #pragma unroll
      for (int rep = 0; rep < RREP; ++rep)
        __hip_atomic_store(xbuf + (size_t)rep * N_RES + row0 + rml, xu,
                           __ATOMIC_RELAXED, __HIP_MEMORY_SCOPE_AGENT);
      out[row0 + rml] = x0;
    }
  }

  // ---- W_res: w[r][k] = W[row0+r][8*tid + k]; contiguous 32B/thread ------
  float w[ROWS][8];
  #pragma unroll
  for (int r = 0; r < ROWS; ++r) {
    const float* p = wres + (size_t)(row0 + r) * N_RES + 8 * tid;
    float4 a = *(const float4*)(p);
    float4 b = *(const float4*)(p + 4);
    w[r][0] = a.x; w[r][1] = a.y; w[r][2] = a.z; w[r][3] = a.w;
    w[r][4] = b.x; w[r][5] = b.y; w[r][6] = b.z; w[r][7] = b.w;
  }

  __shared__ float red[2][4][ROWS];   // [t&1][wave][row] — conflict-free

  // u for t=1
  float u;
  {
    const float* ip = in + N_IN + ((lane >> 3) << 4);
    float uv = 0.f;
    #pragma unroll
    for (int q = 0; q < 4; ++q) {
      float4 iv = *(const float4*)(ip + 4 * q);
      uv = fmaf(wiA[4*q+0], iv.x, uv); uv = fmaf(wiA[4*q+1], iv.y, uv);
      uv = fmaf(wiA[4*q+2], iv.z, uv); uv = fmaf(wiA[4*q+3], iv.w, uv);
    }
    uv += __shfl_xor(uv, 8, 64);
    uv += __shfl_xor(uv, 16, 64);
    uv += __shfl_xor(uv, 32, 64);
    u = uv;
  }
  __syncthreads();

  for (int t = 1; t < T_SEQ; ++t) {
    const int p = t & 1;

    // ---- poll own 8 contiguous x words of row t-1: 4 x u64 loads ---------
    const unsigned long long* xr = (const unsigned long long*)xbuf
        + ((size_t)(t - 1) * RREP + rb) * (N_RES / 2) + 4 * tid;
    unsigned long long xq[4];
    unsigned long long orv;
    do {
      #pragma unroll
      for (int j = 0; j < 4; ++j)
        xq[j] = __hip_atomic_load(xr + j, __ATOMIC_RELAXED,
                                  __HIP_MEMORY_SCOPE_AGENT);
      orv = (xq[0] | xq[1]) | (xq[2] | xq[3]);
    } while (orv & SENTM64);

    asm volatile("s_setprio 3" ::: "memory");   // critical path begins

    // partial matvec: 8 rows x 8 cols (cols 8*tid .. 8*tid+7)
    float x0 = __uint_as_float((unsigned int)xq[0]);
    float x1 = __uint_as_float((unsigned int)(xq[0] >> 32));
    float x2 = __uint_as_float((unsigned int)xq[1]);
    float x3 = __uint_as_float((unsigned int)(xq[1] >> 32));
    float x4 = __uint_as_float((unsigned int)xq[2]);
    float x5 = __uint_as_float((unsigned int)(xq[2] >> 32));
    float x6 = __uint_as_float((unsigned int)xq[3]);
    float x7 = __uint_as_float((unsigned int)(xq[3] >> 32));
    float acc[ROWS];
    #pragma unroll
    for (int r = 0; r < ROWS; ++r) {
      acc[r] = w[r][0]*x0 + w[r][1]*x1 + w[r][2]*x2 + w[r][3]*x3
             + w[r][4]*x4 + w[r][5]*x5 + w[r][6]*x6 + w[r][7]*x7;
    }
    float s = fold_reduce8(acc, lane);   // lane holds full sum of row rml

    if (wave != 0 && lane < ROWS) red[p][wave][rml] = s;
    __syncthreads();

    // wave 0, lanes 0..7 finalize row rml (u held in register, same lane)
    if (tid < ROWS) {
      float tot = s + red[p][1][rml] + red[p][2][rml] + red[p][3][rml];
      float xt = fast_erf(u + tot) * inv;
      unsigned int xu = __float_as_uint(xt);
      unsigned int* dst = xbuf + (size_t)t * RREP * N_RES + row0 + rml;
      #pragma unroll
      for (int rep = 0; rep < RREP; ++rep)
        __hip_atomic_store(dst + (size_t)rep * N_RES, xu,
                           __ATOMIC_RELAXED, __HIP_MEMORY_SCOPE_AGENT);
      out[(size_t)t * N_RES + row0 + rml] = xt;   // plain; after signals
    }
    asm volatile("s_setprio 0" ::: "memory");   // back to poll priority

    // ---- u for t+1: dead-window work (all other blocks still finishing) --
    {
      int tn = (t + 1) & (T_SEQ - 1);           // t+1, wraps harmlessly at end
      const float* ip = in + (size_t)tn * N_IN + ((lane >> 3) << 4);
      float uv = 0.f;
      #pragma unroll
      for (int q = 0; q < 4; ++q) {
        float4 iv = *(const float4*)(ip + 4 * q);
        uv = fmaf(wiA[4*q+0], iv.x, uv); uv = fmaf(wiA[4*q+1], iv.y, uv);
        uv = fmaf(wiA[4*q+2], iv.z, uv); uv = fmaf(wiA[4*q+3], iv.w, uv);
      }
      uv += __shfl_xor(uv, 8, 64);
      uv += __shfl_xor(uv, 16, 64);
      uv += __shfl_xor(uv, 32, 64);
      u = uv;
    }
    // parity LDS buffer + barrier ordering bounds skew <= 1 step
  }
}

// ---------------- fallback (R2 flag barrier) if ws too small ---------------
#define FSTR 4
#define FROWS 16
__global__ __launch_bounds__(256, 1) void esn_recur_flags(
    const float* __restrict__ wres, float* out, int* ws)
{
  const int b = blockIdx.x;
  const int tid = threadIdx.x;
  const int lane = tid & 63;
  const int wave = tid >> 6;
  const int row0 = b * FROWS;
  const float inv = 0.022097086912079608f;

  float w[FROWS][8];
  #pragma unroll
  for (int r = 0; r < FROWS; ++r) {
    const float* p = wres + (size_t)(row0 + r) * N_RES + tid;
    #pragma unroll
    for (int j = 0; j < 8; ++j) w[r][j] = p[j * 256];
  }

  __shared__ float red[FROWS][4];
  int* flags = ws;

  if (tid < FROWS) {
    float u = out[row0 + tid];
    __hip_atomic_store(out + row0 + tid, erff(u) * inv,
                       __ATOMIC_RELAXED, __HIP_MEMORY_SCOPE_AGENT);
  }
  if (wave == 0) {
    asm volatile("s_waitcnt vmcnt(0)" ::: "memory");
    if (lane == 0)
      __hip_atomic_store(flags + b * FSTR, 1, __ATOMIC_RELAXED, __HIP_MEMORY_SCOPE_AGENT);
  }

  for (int t = 1; t < T_SEQ; ++t) {
    if (wave == 0) {
      const int* f0 = flags + lane * FSTR;
      const int* f1 = flags + (lane + 64) * FSTR;
      bool ok;
      do {
        int a = __hip_atomic_load(f0, __ATOMIC_RELAXED, __HIP_MEMORY_SCOPE_AGENT);
        int c = __hip_atomic_load(f1, __ATOMIC_RELAXED, __HIP_MEMORY_SCOPE_AGENT);
        ok = (a >= t) && (c >= t);
      } while (!__all(ok));
    }
    __syncthreads();

    float u = 0.f;
    if (tid < FROWS) u = out[(size_t)t * N_RES + row0 + tid];

    const float* xrow = out + (size_t)(t - 1) * N_RES + tid;
    float x[8];
    #pragma unroll
    for (int j = 0; j < 8; ++j)
      x[j] = __hip_atomic_load(xrow + j * 256, __ATOMIC_RELAXED, __HIP_MEMORY_SCOPE_AGENT);

    float acc[FROWS];
    #pragma unroll
    for (int r = 0; r < FROWS; ++r) {
      acc[r] = w[r][0]*x[0] + w[r][1]*x[1] + w[r][2]*x[2] + w[r][3]*x[3]
             + w[r][4]*x[4] + w[r][5]*x[5] + w[r][6]*x[6] + w[r][7]*x[7];
    }
    #pragma unroll
    for (int m = 1; m < 64; m <<= 1) {
      #pragma unroll
      for (int r = 0; r < FROWS; ++r)
        acc[r] += __shfl_xor(acc[r], m, 64);
    }
    if (lane == 0) {
      #pragma unroll
      for (int r = 0; r < FROWS; ++r) red[r][wave] = acc[r];
    }
    __syncthreads();
    if (tid < FROWS) {
      float s = red[tid][0] + red[tid][1] + red[tid][2] + red[tid][3];
      __hip_atomic_store(out + (size_t)t * N_RES + row0 + tid, erff(u + s) * inv,
                         __ATOMIC_RELAXED, __HIP_MEMORY_SCOPE_AGENT);
    }
    if (wave == 0) {
      asm volatile("s_waitcnt vmcnt(0)" ::: "memory");
      if (lane == 0)
        __hip_atomic_store(flags + b * FSTR, t + 1,
                           __ATOMIC_RELAXED, __HIP_MEMORY_SCOPE_AGENT);
    }
  }
}

extern "C" void kernel_launch(void* const* d_in, const int* in_sizes, int n_in,
                              void* d_out, int out_size, void* d_ws, size_t ws_size,
                              hipStream_t stream)
{
  const float* input = (const float*)d_in[0];
  const float* w_in  = (const float*)d_in[1];
  const float* w_res = (const float*)d_in[2];
  float* out = (float*)d_out;

  const size_t xbytes = (size_t)T_SEQ * N_RES * sizeof(float);  // 16 MiB

  if (ws_size >= (size_t)RREP * xbytes) {
    unsigned int* xbuf = (unsigned int*)d_ws;
    (void)hipMemsetAsync(d_ws, 0x7F, (size_t)RREP * xbytes, stream);  // sentinel
    void* args[] = { (void*)&input, (void*)&w_in, (void*)&w_res,
                     (void*)&out, (void*)&xbuf };
    (void)hipLaunchCooperativeKernel((void*)esn_recur_v18, dim3(NB), dim3(256),
                                     args, 0, stream);
  } else {
    dim3 g1(N_RES / 64, T_SEQ / 64), b1(256);
    hipLaunchKernelGGL(u_gemm, g1, b1, 0, stream, input, w_in, out);
    int* ws = (int*)d_ws;
    size_t clr = ws_size < 4096 ? ws_size : 4096;
    (void)hipMemsetAsync(d_ws, 0, clr, stream);
    void* args[] = { (void*)&w_res, (void*)&out, (void*)&ws };
    (void)hipLaunchCooperativeKernel((void*)esn_recur_flags, dim3(128), dim3(256),
                                     args, 0, stream);
  }
}

// Round 8
// 2647.185 us; speedup vs baseline: 1.0166x; 1.0166x over previous
//
#include <hip/hip_runtime.h>
#include <math.h>

#define N_RES 2048
#define N_IN  128
#define T_SEQ 2048
#define NB    256      // blocks in recurrence kernel (1 per CU)
#define ROWS  8        // rows per block
#define RREP  4        // x replicas
#define SENT  0x7F7F7F7Fu   // init pattern: bit30 set -> reads as phase-1

#define LOAD8(dst, ptr) do { \
  _Pragma("unroll") \
  for (int j = 0; j < 8; ++j) \
    dst[j] = __hip_atomic_load((ptr) + j * 256, __ATOMIC_RELAXED, \
                               __HIP_MEMORY_SCOPE_AGENT); \
} while (0)
#define OR8(a)  (((a[0] | a[1]) | (a[2] | a[3])) | ((a[4] | a[5]) | (a[6] | a[7])))
#define AND8(a) (((a[0] & a[1]) & (a[2] & a[3])) & ((a[4] & a[5]) & (a[6] & a[7])))

// ---------------- Kernel 1: U = input @ W_in^T (fallback path only) -------
__global__ __launch_bounds__(256) void u_gemm(
    const float* __restrict__ in, const float* __restrict__ win,
    float* __restrict__ out)
{
  __shared__ float As[64][65];
  __shared__ float Bs[64][65];
  const int tid = threadIdx.x;
  const int t0 = blockIdx.y * 64;
  const int n0 = blockIdx.x * 64;
  const int tx = tid & 15, ty = tid >> 4;

  float acc[4][4];
  #pragma unroll
  for (int r = 0; r < 4; ++r)
    #pragma unroll
    for (int c = 0; c < 4; ++c) acc[r][c] = 0.f;

  for (int k0 = 0; k0 < N_IN; k0 += 64) {
    __syncthreads();
    #pragma unroll
    for (int i = 0; i < 4; ++i) {
      int idx = tid + i * 256;
      int row = idx >> 4;
      int k4  = (idx & 15) << 2;
      float4 a = *(const float4*)(in  + (size_t)(t0 + row) * N_IN + k0 + k4);
      As[row][k4+0] = a.x; As[row][k4+1] = a.y; As[row][k4+2] = a.z; As[row][k4+3] = a.w;
      float4 b = *(const float4*)(win + (size_t)(n0 + row) * N_IN + k0 + k4);
      Bs[row][k4+0] = b.x; Bs[row][k4+1] = b.y; Bs[row][k4+2] = b.z; Bs[row][k4+3] = b.w;
    }
    __syncthreads();
    for (int k = 0; k < 64; ++k) {
      float a[4], b[4];
      #pragma unroll
      for (int r = 0; r < 4; ++r) a[r] = As[ty*4+r][k];
      #pragma unroll
      for (int c = 0; c < 4; ++c) b[c] = Bs[tx*4+c][k];
      #pragma unroll
      for (int r = 0; r < 4; ++r)
        #pragma unroll
        for (int c = 0; c < 4; ++c) acc[r][c] += a[r] * b[c];
    }
  }
  #pragma unroll
  for (int r = 0; r < 4; ++r) {
    float4 v = make_float4(acc[r][0], acc[r][1], acc[r][2], acc[r][3]);
    *(float4*)(out + (size_t)(t0 + ty*4 + r) * N_RES + n0 + tx*4) = v;
  }
}

// ---- DPP helpers ----------------------------------------------------------
template<int CTRL>
__device__ __forceinline__ float xdpp(float v)
{
  return __uint_as_float(__builtin_amdgcn_update_dpp(
      0, (int)__float_as_uint(v), CTRL, 0xF, 0xF, true));
}
// quad_perm[1,0,3,2] (xor1) = 0xB1 ; quad_perm[2,3,0,1] (xor2) = 0x4E
// row_ror:8 = 0x128 : within 16-lane rows, (i+8)%16 == i^8

// ---- fold-and-keep wave reduction: 8 partials -> 1 full row sum per lane.
// Lane L ends with the complete sum of row rml8(L) =
// (L&1)*4 + ((L>>1)&1)*2 + ((L>>2)&1)  (bijection on 0..7 for lanes 0..7,
// duplicated x8 across the wave).
__device__ __forceinline__ float fold_reduce8(float v[8], int lane)
{
  #pragma unroll
  for (int r = 0; r < 4; ++r) {
    float send = (lane & 1) ? v[r] : v[r + 4];
    float recv = xdpp<0xB1>(send);
    v[r] = ((lane & 1) ? v[r + 4] : v[r]) + recv;
  }
  #pragma unroll
  for (int r = 0; r < 2; ++r) {
    float send = (lane & 2) ? v[r] : v[r + 2];
    float recv = xdpp<0x4E>(send);
    v[r] = ((lane & 2) ? v[r + 2] : v[r]) + recv;
  }
  {
    float send = (lane & 4) ? v[0] : v[1];
    float recv = __shfl_xor(send, 4, 64);
    v[0] = ((lane & 4) ? v[1] : v[0]) + recv;
  }
  v[0] += xdpp<0x128>(v[0]);           // xor8 within 16-lane row (pure add)
  v[0] += __shfl_xor(v[0], 16, 64);
  v[0] += __shfl_xor(v[0], 32, 64);
  return v[0];
}

// ---- branchless fast erf (A&S 7.1.26), abs err <= 1.5e-7 ------------------
// 1/x via v_rcp_f32 (1 ULP, well below poly error). Validated R1-R7.
__device__ __forceinline__ float fast_erf(float a)
{
  float ax = fabsf(a);
  float t  = __builtin_amdgcn_rcpf(fmaf(0.3275911f, ax, 1.0f));
  float p  = fmaf(1.061405429f, t, -1.453152027f);
  p = fmaf(p, t, 1.421413741f);
  p = fmaf(p, t, -0.284496736f);
  p = fmaf(p, t, 0.254829592f);
  p *= t;
  float e = __expf(-ax * ax);
  float r = fmaf(-p, e, 1.0f);
  return copysignf(r, a);
}

// ---------------- Kernel 2: recurrence v19 (= v17 + 2-slot phase arena) ----
// v17 substrate EXACTLY (measured best 2390 us: 256 blocks x 8 rows, 4B
// words, STRIDED tid+256j poll — frozen; v13/v14/v16/v18 all proved any
// poll-layout change regresses). Changed ONLY the arena lifetime: instead
// of fresh HBM-cold lines per step (64 MiB, the 64 MB FETCH + 64 MB WRITE
// in v17's counters, i.e. an HBM-latency first poll round per step), a
// 2-slot x RREP x 2048-word arena (64 KB, LLC-permanent). Validity = free
// bit30 (|x|<=1/sqrt(2048) -> bit30 clear): step t publishes to slot t&1
// with bit30 = (t>>1)&1; reader of t-1 tests all-bit30 == ((t-1)>>1)&1
// (OR-reduce for phase 0, AND-reduce for phase 1). Slot reuse distance 2;
// dependency chain bounds global skew < 2 steps -> race-free (a block at
// step t+2 implies every block consumed step t).
__global__ __launch_bounds__(256, 1) void esn_recur_v19(
    const float* __restrict__ in, const float* __restrict__ win,
    const float* __restrict__ wres, float* __restrict__ out,
    unsigned int* __restrict__ xbuf)
{
  const int tid = threadIdx.x;
  const int lane = tid & 63;
  const int row0 = blockIdx.x * ROWS;
  const int wave = tid >> 6;
  const float inv = 0.022097086912079608f;   // 1/sqrt(2048)
  const int rml = (lane & 1) * 4 + ((lane >> 1) & 1) * 2 + ((lane >> 2) & 1);
  const int rb = blockIdx.x & (RREP - 1);    // replica this block polls

  // ---- W_in slice: wiA[k] = W_in[row0+rml][(lane>>3)*16 + k] -------------
  float wiA[16];
  {
    const float* wp = win + (size_t)(row0 + rml) * N_IN + ((lane >> 3) << 4);
    #pragma unroll
    for (int q = 0; q < 4; ++q) {
      float4 v = *(const float4*)(wp + 4 * q);
      wiA[4*q+0] = v.x; wiA[4*q+1] = v.y; wiA[4*q+2] = v.z; wiA[4*q+3] = v.w;
    }
  }

  // ---- u0 + x0 publish FIRST (slot 0, phase 0: natural bit30=0) ----------
  {
    const float* ip = in + ((lane >> 3) << 4);
    float uv = 0.f;
    #pragma unroll
    for (int q = 0; q < 4; ++q) {
      float4 iv = *(const float4*)(ip + 4 * q);
      uv = fmaf(wiA[4*q+0], iv.x, uv); uv = fmaf(wiA[4*q+1], iv.y, uv);
      uv = fmaf(wiA[4*q+2], iv.z, uv); uv = fmaf(wiA[4*q+3], iv.w, uv);
    }
    uv += __shfl_xor(uv, 8, 64);
    uv += __shfl_xor(uv, 16, 64);
    uv += __shfl_xor(uv, 32, 64);
    if (tid < ROWS) {
      float x0 = fast_erf(uv) * inv;
      unsigned int xu = __float_as_uint(x0);
      #pragma unroll
      for (int rep = 0; rep < RREP; ++rep)
        __hip_atomic_store(xbuf + (size_t)rep * N_RES + row0 + rml, xu,
                           __ATOMIC_RELAXED, __HIP_MEMORY_SCOPE_AGENT);
      out[row0 + rml] = x0;
    }
  }

  // ---- W_res: w[r][j] = W[row0+r][tid + 256*j]; register-resident --------
  float w[ROWS][8];
  #pragma unroll
  for (int r = 0; r < ROWS; ++r) {
    const float* p = wres + (size_t)(row0 + r) * N_RES + tid;
    #pragma unroll
    for (int j = 0; j < 8; ++j) w[r][j] = p[j * 256];
  }

  __shared__ float red[2][4][ROWS];   // [t&1][wave][row] — conflict-free

  // u for t=1
  float u;
  {
    const float* ip = in + N_IN + ((lane >> 3) << 4);
    float uv = 0.f;
    #pragma unroll
    for (int q = 0; q < 4; ++q) {
      float4 iv = *(const float4*)(ip + 4 * q);
      uv = fmaf(wiA[4*q+0], iv.x, uv); uv = fmaf(wiA[4*q+1], iv.y, uv);
      uv = fmaf(wiA[4*q+2], iv.z, uv); uv = fmaf(wiA[4*q+3], iv.w, uv);
    }
    uv += __shfl_xor(uv, 8, 64);
    uv += __shfl_xor(uv, 16, 64);
    uv += __shfl_xor(uv, 32, 64);
    u = uv;
  }
  __syncthreads();

  for (int t = 1; t < T_SEQ; ++t) {
    const int p = t & 1;

    // ---- poll own 8 x words of row t-1 in slot (t-1)&1, strided ----------
    // expected phase bit30 = ((t-1)>>1)&1; both arms byte-identical loads
    const unsigned int* xr = xbuf + ((size_t)((t - 1) & 1) * RREP + rb) * N_RES + tid;
    unsigned int xb[8];
    if (((t - 1) >> 1) & 1) {
      unsigned int av;
      do {
        LOAD8(xb, xr);
        av = AND8(xb);
      } while (!(av & 0x40000000u));
    } else {
      unsigned int orv;
      do {
        LOAD8(xb, xr);
        orv = OR8(xb);
      } while (orv & 0x40000000u);
    }

    asm volatile("s_setprio 3" ::: "memory");   // critical path begins

    // strip phase bit (no-op for phase 0 words)
    #pragma unroll
    for (int j = 0; j < 8; ++j) xb[j] &= 0xBFFFFFFFu;

    // partial matvec: 8 rows x 8 cols
    float acc[ROWS];
    #pragma unroll
    for (int r = 0; r < ROWS; ++r) {
      acc[r] = w[r][0]*__uint_as_float(xb[0]) + w[r][1]*__uint_as_float(xb[1])
             + w[r][2]*__uint_as_float(xb[2]) + w[r][3]*__uint_as_float(xb[3])
             + w[r][4]*__uint_as_float(xb[4]) + w[r][5]*__uint_as_float(xb[5])
             + w[r][6]*__uint_as_float(xb[6]) + w[r][7]*__uint_as_float(xb[7]);
    }
    float s = fold_reduce8(acc, lane);   // lane holds full sum of row rml

    if (wave != 0 && lane < ROWS) red[p][wave][rml] = s;
    __syncthreads();

    // wave 0, lanes 0..7 finalize row rml (u held in register, same lane)
    if (tid < ROWS) {
      float tot = s + red[p][1][rml] + red[p][2][rml] + red[p][3][rml];
      float xt = fast_erf(u + tot) * inv;
      unsigned int xu = __float_as_uint(xt) | ((unsigned int)((t >> 1) & 1) << 30);
      unsigned int* dst = xbuf + (size_t)(t & 1) * RREP * N_RES + row0 + rml;
      #pragma unroll
      for (int rep = 0; rep < RREP; ++rep)
        __hip_atomic_store(dst + (size_t)rep * N_RES, xu,
                           __ATOMIC_RELAXED, __HIP_MEMORY_SCOPE_AGENT);
      out[(size_t)t * N_RES + row0 + rml] = xt;   // plain; true float bits
    }
    asm volatile("s_setprio 0" ::: "memory");   // back to poll priority

    // ---- u for t+1: dead-window work (all other blocks still finishing) --
    {
      int tn = (t + 1) & (T_SEQ - 1);           // t+1, wraps harmlessly at end
      const float* ip = in + (size_t)tn * N_IN + ((lane >> 3) << 4);
      float uv = 0.f;
      #pragma unroll
      for (int q = 0; q < 4; ++q) {
        float4 iv = *(const float4*)(ip + 4 * q);
        uv = fmaf(wiA[4*q+0], iv.x, uv); uv = fmaf(wiA[4*q+1], iv.y, uv);
        uv = fmaf(wiA[4*q+2], iv.z, uv); uv = fmaf(wiA[4*q+3], iv.w, uv);
      }
      uv += __shfl_xor(uv, 8, 64);
      uv += __shfl_xor(uv, 16, 64);
      uv += __shfl_xor(uv, 32, 64);
      u = uv;
    }
    // parity LDS buffer + barrier ordering bounds skew <= 1 step in-block;
    // data dependency bounds global skew < 2 steps (slot-reuse safety)
  }
}

// ---------------- fallback (R2 flag barrier) if ws too small ---------------
#define FSTR 4
#define FROWS 16
__global__ __launch_bounds__(256, 1) void esn_recur_flags(
    const float* __restrict__ wres, float* out, int* ws)
{
  const int b = blockIdx.x;
  const int tid = threadIdx.x;
  const int lane = tid & 63;
  const int wave = tid >> 6;
  const int row0 = b * FROWS;
  const float inv = 0.022097086912079608f;

  float w[FROWS][8];
  #pragma unroll
  for (int r = 0; r < FROWS; ++r) {
    const float* p = wres + (size_t)(row0 + r) * N_RES + tid;
    #pragma unroll
    for (int j = 0; j < 8; ++j) w[r][j] = p[j * 256];
  }

  __shared__ float red[FROWS][4];
  int* flags = ws;

  if (tid < FROWS) {
    float u = out[row0 + tid];
    __hip_atomic_store(out + row0 + tid, erff(u) * inv,
                       __ATOMIC_RELAXED, __HIP_MEMORY_SCOPE_AGENT);
  }
  if (wave == 0) {
    asm volatile("s_waitcnt vmcnt(0)" ::: "memory");
    if (lane == 0)
      __hip_atomic_store(flags + b * FSTR, 1, __ATOMIC_RELAXED, __HIP_MEMORY_SCOPE_AGENT);
  }

  for (int t = 1; t < T_SEQ; ++t) {
    if (wave == 0) {
      const int* f0 = flags + lane * FSTR;
      const int* f1 = flags + (lane + 64) * FSTR;
      bool ok;
      do {
        int a = __hip_atomic_load(f0, __ATOMIC_RELAXED, __HIP_MEMORY_SCOPE_AGENT);
        int c = __hip_atomic_load(f1, __ATOMIC_RELAXED, __HIP_MEMORY_SCOPE_AGENT);
        ok = (a >= t) && (c >= t);
      } while (!__all(ok));
    }
    __syncthreads();

    float u = 0.f;
    if (tid < FROWS) u = out[(size_t)t * N_RES + row0 + tid];

    const float* xrow = out + (size_t)(t - 1) * N_RES + tid;
    float x[8];
    #pragma unroll
    for (int j = 0; j < 8; ++j)
      x[j] = __hip_atomic_load(xrow + j * 256, __ATOMIC_RELAXED, __HIP_MEMORY_SCOPE_AGENT);

    float acc[FROWS];
    #pragma unroll
    for (int r = 0; r < FROWS; ++r) {
      acc[r] = w[r][0]*x[0] + w[r][1]*x[1] + w[r][2]*x[2] + w[r][3]*x[3]
             + w[r][4]*x[4] + w[r][5]*x[5] + w[r][6]*x[6] + w[r][7]*x[7];
    }
    #pragma unroll
    for (int m = 1; m < 64; m <<= 1) {
      #pragma unroll
      for (int r = 0; r < FROWS; ++r)
        acc[r] += __shfl_xor(acc[r], m, 64);
    }
    if (lane == 0) {
      #pragma unroll
      for (int r = 0; r < FROWS; ++r) red[r][wave] = acc[r];
    }
    __syncthreads();
    if (tid < FROWS) {
      float s = red[tid][0] + red[tid][1] + red[tid][2] + red[tid][3];
      __hip_atomic_store(out + (size_t)t * N_RES + row0 + tid, erff(u + s) * inv,
                         __ATOMIC_RELAXED, __HIP_MEMORY_SCOPE_AGENT);
    }
    if (wave == 0) {
      asm volatile("s_waitcnt vmcnt(0)" ::: "memory");
      if (lane == 0)
        __hip_atomic_store(flags + b * FSTR, t + 1,
                           __ATOMIC_RELAXED, __HIP_MEMORY_SCOPE_AGENT);
    }
  }
}

extern "C" void kernel_launch(void* const* d_in, const int* in_sizes, int n_in,
                              void* d_out, int out_size, void* d_ws, size_t ws_size,
                              hipStream_t stream)
{
  const float* input = (const float*)d_in[0];
  const float* w_in  = (const float*)d_in[1];
  const float* w_res = (const float*)d_in[2];
  float* out = (float*)d_out;

  const size_t arena = (size_t)2 * RREP * N_RES * sizeof(unsigned int); // 64 KiB

  if (ws_size >= arena) {
    unsigned int* xbuf = (unsigned int*)d_ws;
    (void)hipMemsetAsync(d_ws, 0xFF, arena, stream);  // bit30=1: phase-1 look,
                                                      // first reads expect phase 0
    void* args[] = { (void*)&input, (void*)&w_in, (void*)&w_res,
                     (void*)&out, (void*)&xbuf };
    (void)hipLaunchCooperativeKernel((void*)esn_recur_v19, dim3(NB), dim3(256),
                                     args, 0, stream);
  } else {
    dim3 g1(N_RES / 64, T_SEQ / 64), b1(256);
    hipLaunchKernelGGL(u_gemm, g1, b1, 0, stream, input, w_in, out);
    int* ws = (int*)d_ws;
    size_t clr = ws_size < 4096 ? ws_size : 4096;
    (void)hipMemsetAsync(d_ws, 0, clr, stream);
    void* args[] = { (void*)&w_res, (void*)&out, (void*)&ws };
    (void)hipLaunchCooperativeKernel((void*)esn_recur_flags, dim3(128), dim3(256),
                                     args, 0, stream);
  }
}

// Round 9
// 2384.523 us; speedup vs baseline: 1.1286x; 1.1102x over previous
//
#include <hip/hip_runtime.h>
#include <math.h>

#define N_RES 2048
#define N_IN  128
#define T_SEQ 2048
#define NB    512      // blocks in recurrence kernel (2 per CU)
#define ROWS  4        // rows per block
#define RREP  4        // x replicas
#define SENT  0x7F7F7F7Fu   // sentinel; bit30 set. |x|<=0.0222 -> bit30 clear

#define LOAD8(dst, ptr) do { \
  _Pragma("unroll") \
  for (int j = 0; j < 8; ++j) \
    dst[j] = __hip_atomic_load((ptr) + j * 256, __ATOMIC_RELAXED, \
                               __HIP_MEMORY_SCOPE_AGENT); \
} while (0)
#define OR8(a) (((a[0] | a[1]) | (a[2] | a[3])) | ((a[4] | a[5]) | (a[6] | a[7])))

// ---------------- Kernel 1: U = input @ W_in^T (fallback path only) -------
__global__ __launch_bounds__(256) void u_gemm(
    const float* __restrict__ in, const float* __restrict__ win,
    float* __restrict__ out)
{
  __shared__ float As[64][65];
  __shared__ float Bs[64][65];
  const int tid = threadIdx.x;
  const int t0 = blockIdx.y * 64;
  const int n0 = blockIdx.x * 64;
  const int tx = tid & 15, ty = tid >> 4;

  float acc[4][4];
  #pragma unroll
  for (int r = 0; r < 4; ++r)
    #pragma unroll
    for (int c = 0; c < 4; ++c) acc[r][c] = 0.f;

  for (int k0 = 0; k0 < N_IN; k0 += 64) {
    __syncthreads();
    #pragma unroll
    for (int i = 0; i < 4; ++i) {
      int idx = tid + i * 256;
      int row = idx >> 4;
      int k4  = (idx & 15) << 2;
      float4 a = *(const float4*)(in  + (size_t)(t0 + row) * N_IN + k0 + k4);
      As[row][k4+0] = a.x; As[row][k4+1] = a.y; As[row][k4+2] = a.z; As[row][k4+3] = a.w;
      float4 b = *(const float4*)(win + (size_t)(n0 + row) * N_IN + k0 + k4);
      Bs[row][k4+0] = b.x; Bs[row][k4+1] = b.y; Bs[row][k4+2] = b.z; Bs[row][k4+3] = b.w;
    }
    __syncthreads();
    for (int k = 0; k < 64; ++k) {
      float a[4], b[4];
      #pragma unroll
      for (int r = 0; r < 4; ++r) a[r] = As[ty*4+r][k];
      #pragma unroll
      for (int c = 0; c < 4; ++c) b[c] = Bs[tx*4+c][k];
      #pragma unroll
      for (int r = 0; r < 4; ++r)
        #pragma unroll
        for (int c = 0; c < 4; ++c) acc[r][c] += a[r] * b[c];
    }
  }
  #pragma unroll
  for (int r = 0; r < 4; ++r) {
    float4 v = make_float4(acc[r][0], acc[r][1], acc[r][2], acc[r][3]);
    *(float4*)(out + (size_t)(t0 + ty*4 + r) * N_RES + n0 + tx*4) = v;
  }
}

// ---- DPP helpers ----------------------------------------------------------
template<int CTRL>
__device__ __forceinline__ float xdpp(float v)
{
  return __uint_as_float(__builtin_amdgcn_update_dpp(
      0, (int)__float_as_uint(v), CTRL, 0xF, 0xF, true));
}
// quad_perm[1,0,3,2] (xor1) = 0xB1 ; quad_perm[2,3,0,1] (xor2) = 0x4E
// row_ror:8 = 0x128 : within 16-lane rows, (i+8)%16 == i^8

// ---- fold-and-keep wave reduction: 4 partials -> 1 full row sum per lane.
// (proven correct in v13/R1). Lane L ends with the full sum of row
// rml4(L) = (L&1)*2 + ((L>>1)&1)  (bijection on 0..3 for lanes 0..3,
// duplicated x16 across the wave).
__device__ __forceinline__ float fold_reduce4(float v[4], int lane)
{
  #pragma unroll
  for (int r = 0; r < 2; ++r) {
    float send = (lane & 1) ? v[r] : v[r + 2];
    float recv = xdpp<0xB1>(send);
    v[r] = ((lane & 1) ? v[r + 2] : v[r]) + recv;
  }
  {
    float send = (lane & 2) ? v[0] : v[1];
    float recv = xdpp<0x4E>(send);
    v[0] = ((lane & 2) ? v[1] : v[0]) + recv;
  }
  v[0] += __shfl_xor(v[0], 4, 64);
  v[0] += xdpp<0x128>(v[0]);           // xor8 within 16-lane row (pure add)
  v[0] += __shfl_xor(v[0], 16, 64);
  v[0] += __shfl_xor(v[0], 32, 64);
  return v[0];
}

// ---- branchless fast erf (A&S 7.1.26), abs err <= 1.5e-7 ------------------
// 1/x via v_rcp_f32 (1 ULP, well below poly error). Validated R1-R8.
__device__ __forceinline__ float fast_erf(float a)
{
  float ax = fabsf(a);
  float t  = __builtin_amdgcn_rcpf(fmaf(0.3275911f, ax, 1.0f));
  float p  = fmaf(1.061405429f, t, -1.453152027f);
  p = fmaf(p, t, 1.421413741f);
  p = fmaf(p, t, -0.284496736f);
  p = fmaf(p, t, 0.254829592f);
  p *= t;
  float e = __expf(-ax * ax);
  float r = fmaf(-p, e, 1.0f);
  return copysignf(r, a);
}

// ---------------- Kernel 2: recurrence v20 (= v17 on 512 blocks x 4 rows) --
// v17 substrate EXACTLY (measured best 2390 us): 4B sentinel, fresh lines,
// RREP=4, STRIDED tid+256j single-buffer poll (frozen after v13/v14/v16/
// v18/v19 all regressed), parity LDS combine, setprio, fused U. Changed
// ONLY block decomposition: 512 blocks x 4 rows (2 blocks/CU). Post-detect
// path halves again (32 FMAs, fold_reduce4, 4-row combine) — the R6
// mechanism (max-over-publishers amplifies per-block path reduction).
// Sibling block's prio-3 finalize preempts the other's prio-0 poll.
__global__ __launch_bounds__(256, 2) void esn_recur_v20(
    const float* __restrict__ in, const float* __restrict__ win,
    const float* __restrict__ wres, float* __restrict__ out,
    unsigned int* __restrict__ xbuf)
{
  const int tid = threadIdx.x;
  const int lane = tid & 63;
  const int row0 = blockIdx.x * ROWS;
  const int wave = tid >> 6;
  const float inv = 0.022097086912079608f;   // 1/sqrt(2048)
  const int rml = (lane & 1) * 2 + ((lane >> 1) & 1);
  const int rb = blockIdx.x & (RREP - 1);    // replica this block polls

  // ---- W_in slice: wiA[k] = W_in[row0+rml][(lane>>2)*8 + k] --------------
  float wiA[8];
  {
    const float* wp = win + (size_t)(row0 + rml) * N_IN + ((lane >> 2) << 3);
    float4 a = *(const float4*)(wp);
    float4 b = *(const float4*)(wp + 4);
    wiA[0] = a.x; wiA[1] = a.y; wiA[2] = a.z; wiA[3] = a.w;
    wiA[4] = b.x; wiA[5] = b.y; wiA[6] = b.z; wiA[7] = b.w;
  }

  // ---- u0 + x0 publish FIRST (unblocks everyone's t=1 poll early) --------
  {
    const float* ip = in + ((lane >> 2) << 3);
    float4 a = *(const float4*)(ip);
    float4 b = *(const float4*)(ip + 4);
    float uv = wiA[0]*a.x + wiA[1]*a.y + wiA[2]*a.z + wiA[3]*a.w
             + wiA[4]*b.x + wiA[5]*b.y + wiA[6]*b.z + wiA[7]*b.w;
    uv += __shfl_xor(uv, 4, 64);
    uv += __shfl_xor(uv, 8, 64);
    uv += __shfl_xor(uv, 16, 64);
    uv += __shfl_xor(uv, 32, 64);
    if (tid < ROWS) {
      float x0 = fast_erf(uv) * inv;
      unsigned int xu = __float_as_uint(x0);
      #pragma unroll
      for (int rep = 0; rep < RREP; ++rep)
        __hip_atomic_store(xbuf + (size_t)rep * N_RES + row0 + rml, xu,
                           __ATOMIC_RELAXED, __HIP_MEMORY_SCOPE_AGENT);
      out[row0 + rml] = x0;
    }
  }

  // ---- W_res: w[r][j] = W[row0+r][tid + 256*j]; register-resident --------
  float w[ROWS][8];
  #pragma unroll
  for (int r = 0; r < ROWS; ++r) {
    const float* p = wres + (size_t)(row0 + r) * N_RES + tid;
    #pragma unroll
    for (int j = 0; j < 8; ++j) w[r][j] = p[j * 256];
  }

  __shared__ float red[2][4][ROWS];   // [t&1][wave][row] — conflict-free

  // u for t=1
  float u;
  {
    const float* ip = in + N_IN + ((lane >> 2) << 3);
    float4 a = *(const float4*)(ip);
    float4 b = *(const float4*)(ip + 4);
    float uv = wiA[0]*a.x + wiA[1]*a.y + wiA[2]*a.z + wiA[3]*a.w
             + wiA[4]*b.x + wiA[5]*b.y + wiA[6]*b.z + wiA[7]*b.w;
    uv += __shfl_xor(uv, 4, 64);
    uv += __shfl_xor(uv, 8, 64);
    uv += __shfl_xor(uv, 16, 64);
    uv += __shfl_xor(uv, 32, 64);
    u = uv;
  }
  __syncthreads();

  for (int t = 1; t < T_SEQ; ++t) {
    const int p = t & 1;

    // ---- poll own 8 x words of row t-1 (bit-30 sentinel test), prio 0 ----
    // byte-identical to v17 (frozen poll substrate)
    const unsigned int* xr = xbuf + ((size_t)(t - 1) * RREP + rb) * N_RES + tid;
    unsigned int xb[8];
    unsigned int orv;
    do {
      LOAD8(xb, xr);
      orv = OR8(xb);
    } while (orv & 0x40000000u);

    asm volatile("s_setprio 3" ::: "memory");   // critical path begins

    // partial matvec: 4 rows x 8 cols
    float acc[ROWS];
    #pragma unroll
    for (int r = 0; r < ROWS; ++r) {
      acc[r] = w[r][0]*__uint_as_float(xb[0]) + w[r][1]*__uint_as_float(xb[1])
             + w[r][2]*__uint_as_float(xb[2]) + w[r][3]*__uint_as_float(xb[3])
             + w[r][4]*__uint_as_float(xb[4]) + w[r][5]*__uint_as_float(xb[5])
             + w[r][6]*__uint_as_float(xb[6]) + w[r][7]*__uint_as_float(xb[7]);
    }
    float s = fold_reduce4(acc, lane);   // lane holds full sum of row rml

    if (wave != 0 && lane < ROWS) red[p][wave][rml] = s;
    __syncthreads();

    // wave 0, lanes 0..3 finalize row rml (u held in register, same lane)
    if (tid < ROWS) {
      float tot = s + red[p][1][rml] + red[p][2][rml] + red[p][3][rml];
      float xt = fast_erf(u + tot) * inv;
      unsigned int xu = __float_as_uint(xt);
      unsigned int* dst = xbuf + (size_t)t * RREP * N_RES + row0 + rml;
      #pragma unroll
      for (int rep = 0; rep < RREP; ++rep)
        __hip_atomic_store(dst + (size_t)rep * N_RES, xu,
                           __ATOMIC_RELAXED, __HIP_MEMORY_SCOPE_AGENT);
      out[(size_t)t * N_RES + row0 + rml] = xt;   // plain; after signals
    }
    asm volatile("s_setprio 0" ::: "memory");   // back to poll priority

    // ---- u for t+1: dead-window work (all other blocks still finishing) --
    {
      int tn = (t + 1) & (T_SEQ - 1);           // t+1, wraps harmlessly at end
      const float* ip = in + (size_t)tn * N_IN + ((lane >> 2) << 3);
      float4 a = *(const float4*)(ip);
      float4 b = *(const float4*)(ip + 4);
      float uv = wiA[0]*a.x + wiA[1]*a.y + wiA[2]*a.z + wiA[3]*a.w
               + wiA[4]*b.x + wiA[5]*b.y + wiA[6]*b.z + wiA[7]*b.w;
      uv += __shfl_xor(uv, 4, 64);
      uv += __shfl_xor(uv, 8, 64);
      uv += __shfl_xor(uv, 16, 64);
      uv += __shfl_xor(uv, 32, 64);
      u = uv;
    }
    // parity LDS buffer + barrier ordering bounds skew <= 1 step
  }
}

// ---------------- fallback (R2 flag barrier) if ws too small ---------------
#define FSTR 4
#define FROWS 16
__global__ __launch_bounds__(256, 1) void esn_recur_flags(
    const float* __restrict__ wres, float* out, int* ws)
{
  const int b = blockIdx.x;
  const int tid = threadIdx.x;
  const int lane = tid & 63;
  const int wave = tid >> 6;
  const int row0 = b * FROWS;
  const float inv = 0.022097086912079608f;

  float w[FROWS][8];
  #pragma unroll
  for (int r = 0; r < FROWS; ++r) {
    const float* p = wres + (size_t)(row0 + r) * N_RES + tid;
    #pragma unroll
    for (int j = 0; j < 8; ++j) w[r][j] = p[j * 256];
  }

  __shared__ float red[FROWS][4];
  int* flags = ws;

  if (tid < FROWS) {
    float u = out[row0 + tid];
    __hip_atomic_store(out + row0 + tid, erff(u) * inv,
                       __ATOMIC_RELAXED, __HIP_MEMORY_SCOPE_AGENT);
  }
  if (wave == 0) {
    asm volatile("s_waitcnt vmcnt(0)" ::: "memory");
    if (lane == 0)
      __hip_atomic_store(flags + b * FSTR, 1, __ATOMIC_RELAXED, __HIP_MEMORY_SCOPE_AGENT);
  }

  for (int t = 1; t < T_SEQ; ++t) {
    if (wave == 0) {
      const int* f0 = flags + lane * FSTR;
      const int* f1 = flags + (lane + 64) * FSTR;
      bool ok;
      do {
        int a = __hip_atomic_load(f0, __ATOMIC_RELAXED, __HIP_MEMORY_SCOPE_AGENT);
        int c = __hip_atomic_load(f1, __ATOMIC_RELAXED, __HIP_MEMORY_SCOPE_AGENT);
        ok = (a >= t) && (c >= t);
      } while (!__all(ok));
    }
    __syncthreads();

    float u = 0.f;
    if (tid < FROWS) u = out[(size_t)t * N_RES + row0 + tid];

    const float* xrow = out + (size_t)(t - 1) * N_RES + tid;
    float x[8];
    #pragma unroll
    for (int j = 0; j < 8; ++j)
      x[j] = __hip_atomic_load(xrow + j * 256, __ATOMIC_RELAXED, __HIP_MEMORY_SCOPE_AGENT);

    float acc[FROWS];
    #pragma unroll
    for (int r = 0; r < FROWS; ++r) {
      acc[r] = w[r][0]*x[0] + w[r][1]*x[1] + w[r][2]*x[2] + w[r][3]*x[3]
             + w[r][4]*x[4] + w[r][5]*x[5] + w[r][6]*x[6] + w[r][7]*x[7];
    }
    #pragma unroll
    for (int m = 1; m < 64; m <<= 1) {
      #pragma unroll
      for (int r = 0; r < FROWS; ++r)
        acc[r] += __shfl_xor(acc[r], m, 64);
    }
    if (lane == 0) {
      #pragma unroll
      for (int r = 0; r < FROWS; ++r) red[r][wave] = acc[r];
    }
    __syncthreads();
    if (tid < FROWS) {
      float s = red[tid][0] + red[tid][1] + red[tid][2] + red[tid][3];
      __hip_atomic_store(out + (size_t)t * N_RES + row0 + tid, erff(u + s) * inv,
                         __ATOMIC_RELAXED, __HIP_MEMORY_SCOPE_AGENT);
    }
    if (wave == 0) {
      asm volatile("s_waitcnt vmcnt(0)" ::: "memory");
      if (lane == 0)
        __hip_atomic_store(flags + b * FSTR, t + 1,
                           __ATOMIC_RELAXED, __HIP_MEMORY_SCOPE_AGENT);
    }
  }
}

extern "C" void kernel_launch(void* const* d_in, const int* in_sizes, int n_in,
                              void* d_out, int out_size, void* d_ws, size_t ws_size,
                              hipStream_t stream)
{
  const float* input = (const float*)d_in[0];
  const float* w_in  = (const float*)d_in[1];
  const float* w_res = (const float*)d_in[2];
  float* out = (float*)d_out;

  const size_t xbytes = (size_t)T_SEQ * N_RES * sizeof(float);  // 16 MiB

  if (ws_size >= (size_t)RREP * xbytes) {
    unsigned int* xbuf = (unsigned int*)d_ws;
    (void)hipMemsetAsync(d_ws, 0x7F, (size_t)RREP * xbytes, stream);  // sentinel
    void* args[] = { (void*)&input, (void*)&w_in, (void*)&w_res,
                     (void*)&out, (void*)&xbuf };
    (void)hipLaunchCooperativeKernel((void*)esn_recur_v20, dim3(NB), dim3(256),
                                     args, 0, stream);
  } else {
    dim3 g1(N_RES / 64, T_SEQ / 64), b1(256);
    hipLaunchKernelGGL(u_gemm, g1, b1, 0, stream, input, w_in, out);
    int* ws = (int*)d_ws;
    size_t clr = ws_size < 4096 ? ws_size : 4096;
    (void)hipMemsetAsync(d_ws, 0, clr, stream);
    void* args[] = { (void*)&w_res, (void*)&out, (void*)&ws };
    (void)hipLaunchCooperativeKernel((void*)esn_recur_flags, dim3(128), dim3(256),
                                     args, 0, stream);
  }
}